// Round 4
// baseline (307.582 us; speedup 1.0000x reference)
//
#include <hip/hip_runtime.h>

// Problem: x:[B=64,S=2048,K=256] f32, W:[K=256,D=512] f32
// out[b,d] = mean_s(x) @ W  -> [64,512] f32
// Single kernel: block (b,c) seq-reduces 64 rows of x into part[b][c][:],
// then the LAST block to finish for batch b (atomic counter) reduces the 32
// partials and does the 256x512 dot — overlapped with the streaming tail.
// Finisher sums chunks in fixed order c=0..31 -> bitwise deterministic.

typedef float f32x4 __attribute__((ext_vector_type(4)));

#define BB 64
#define SS 2048
#define KK 256
#define DD 512
#define CHUNKS 32
#define RPC (SS / CHUNKS)           // 64 rows per chunk
#define PART_FLOATS (BB * CHUNKS * KK)

__global__ __launch_bounds__(256) void fused_kernel(const float* __restrict__ x,
                                                    const float* __restrict__ w,
                                                    float* __restrict__ out,
                                                    float* __restrict__ part,
                                                    unsigned int* __restrict__ cnt) {
    const int blk = blockIdx.x;
    const int b  = blk >> 5;        // / CHUNKS
    const int c  = blk & 31;        // % CHUNKS
    const int t  = threadIdx.x;
    const int tx = t & 63;          // f32x4 lane across K (64*4 = 256)
    const int ty = t >> 6;          // 0..3

    // ---- Phase 1: stream 64 rows, plain coalesced f32x4 loads ----
    const f32x4* xp = (const f32x4*)(x + ((size_t)b * SS + (size_t)c * RPC) * KK) + tx;

    f32x4 acc = {0.f, 0.f, 0.f, 0.f};
    #pragma unroll
    for (int i = 0; i < RPC / 4; ++i)
        acc += xp[(size_t)(i * 4 + ty) * (KK / 4)];

    __shared__ f32x4 smem[4][64];
    smem[ty][tx] = acc;
    __syncthreads();
    if (ty == 0) {
        f32x4 r = (smem[0][tx] + smem[1][tx]) + (smem[2][tx] + smem[3][tx]);
        ((f32x4*)(part + ((size_t)b * CHUNKS + c) * KK))[tx] = r;
    }

    // ---- Publish + elect finisher ----
    __syncthreads();
    __threadfence();                // release: partial stores -> device scope
    __shared__ int last;
    if (t == 0) {
        unsigned int old = atomicAdd(&cnt[b], 1u);
        last = (old == CHUNKS - 1);
    }
    __syncthreads();
    if (!last) return;
    __threadfence();                // acquire: invalidate L1 before reading peers

    // ---- Phase 2 (finisher only): mean + dot ----
    __shared__ float xm[KK];
    {
        float s = 0.f;
        const float* pp = part + (size_t)b * CHUNKS * KK + t;
        #pragma unroll
        for (int cc = 0; cc < CHUNKS; ++cc) s += pp[cc * KK];   // fixed order
        xm[t] = s * (1.0f / SS);
    }
    __syncthreads();

    // 256 threads: col4 = float4 column (128 per row), kg = k-half (2x128).
    const int col4 = t & 127;
    const int kg   = t >> 7;
    const f32x4* w4 = (const f32x4*)w;

    f32x4 o = {0.f, 0.f, 0.f, 0.f};
    const int k0 = kg * 128;
    #pragma unroll 8
    for (int k = k0; k < k0 + 128; ++k) {
        const float xv = xm[k];                       // LDS broadcast
        o += xv * w4[(size_t)k * (DD / 4) + col4];    // 16B coalesced, L2-hot
    }

    __shared__ f32x4 red[128];
    if (kg) red[col4] = o;
    __syncthreads();
    if (!kg) {
        o += red[col4];
        ((f32x4*)out)[(size_t)b * (DD / 4) + col4] = o;
    }
}

extern "C" void kernel_launch(void* const* d_in, const int* in_sizes, int n_in,
                              void* d_out, int out_size, void* d_ws, size_t ws_size,
                              hipStream_t stream) {
    const float* x = (const float*)d_in[0];
    const float* w = (const float*)d_in[1];
    float* out  = (float*)d_out;
    float* part = (float*)d_ws;                                   // 2 MiB
    unsigned int* cnt = (unsigned int*)((char*)d_ws + (size_t)PART_FLOATS * 4);

    hipMemsetAsync(cnt, 0, BB * sizeof(unsigned int), stream);    // zero counters
    fused_kernel<<<BB * CHUNKS, 256, 0, stream>>>(x, w, out, part, cnt);
}

// Round 5
// 28.766 us; speedup vs baseline: 10.6926x; 10.6926x over previous
//
#include <hip/hip_runtime.h>

// Problem: x:[B=64,S=2048,K=256] f32, W:[K=256,D=512] f32
// out[b,d] = mean_s(x) @ W  -> [64,512] f32
// Two kernels: stage A seq-reduces x into [B,CHUNKS,K] partials (HBM/L3-bound,
// 128 MiB read — keep loads CACHED, x is partially L3-resident across replays);
// stage B (256 blocks, split-k 8) finishes mean + tiny GEMM.

typedef float f32x4 __attribute__((ext_vector_type(4)));

#define BB 64
#define SS 2048
#define KK 256
#define DD 512
#define CHUNKS 16
#define RPC (SS / CHUNKS)  // 128 rows per chunk

// Stage A: one block per (b, chunk). 256 threads = 64 f32x4 lanes across K
// x 4 rows in s; 32 row-iterations each. Plain loads -> L3 hits count.
__global__ __launch_bounds__(256) void partial_sum_kernel(const float* __restrict__ x,
                                                          float* __restrict__ part) {
    const int blk = blockIdx.x;          // b * CHUNKS + c
    const int b  = blk >> 4;
    const int c  = blk & 15;
    const int t  = threadIdx.x;
    const int tx = t & 63;               // f32x4 index across K (64*4 = 256)
    const int ty = t >> 6;               // 0..3

    const f32x4* xp = (const f32x4*)(x + ((size_t)b * SS + (size_t)c * RPC) * KK) + tx;

    f32x4 acc = {0.f, 0.f, 0.f, 0.f};
    #pragma unroll
    for (int i = 0; i < RPC / 4; ++i)
        acc += xp[(size_t)(i * 4 + ty) * (KK / 4)];

    __shared__ f32x4 smem[4][64];
    smem[ty][tx] = acc;
    __syncthreads();

    if (ty == 0) {
        f32x4 r = (smem[0][tx] + smem[1][tx]) + (smem[2][tx] + smem[3][tx]);
        ((f32x4*)(part + ((size_t)b * CHUNKS + c) * KK))[tx] = r;
    }
}

// Stage B: 4 blocks per b. Block (b,dq): 128 output cols (32 f32x4),
// split-k 8-way across thread groups, LDS reduce, store.
__global__ __launch_bounds__(256) void finish_kernel(const float* __restrict__ part,
                                                     const float* __restrict__ w,
                                                     float* __restrict__ out) {
    const int b  = blockIdx.x >> 2;
    const int dq = blockIdx.x & 3;
    const int t  = threadIdx.x;          // 0..255

    __shared__ float xm[KK];
    {
        float s = 0.f;
        const float* pp = part + (size_t)b * CHUNKS * KK + t;
        #pragma unroll
        for (int c = 0; c < CHUNKS; ++c) s += pp[c * KK];       // fixed order
        xm[t] = s * (1.0f / SS);
    }
    __syncthreads();

    const int col4 = dq * 32 + (t & 31); // f32x4 column in [0, 128)
    const int kg   = t >> 5;             // k-group 0..7, 32 k's each
    const f32x4* w4 = (const f32x4*)w;

    f32x4 acc = {0.f, 0.f, 0.f, 0.f};
    #pragma unroll
    for (int kk = 0; kk < 32; ++kk) {
        const int k = kg * 32 + kk;
        acc += xm[k] * w4[(size_t)k * (DD / 4) + col4];         // 16B coalesced
    }

    __shared__ f32x4 red[8][32];
    if (kg) red[kg][t & 31] = acc;
    __syncthreads();
    if (kg == 0) {
        #pragma unroll
        for (int g = 1; g < 8; ++g) acc += red[g][t];
        ((f32x4*)out)[(size_t)b * (DD / 4) + col4] = acc;
    }
}

extern "C" void kernel_launch(void* const* d_in, const int* in_sizes, int n_in,
                              void* d_out, int out_size, void* d_ws, size_t ws_size,
                              hipStream_t stream) {
    const float* x = (const float*)d_in[0];
    const float* w = (const float*)d_in[1];
    float* out  = (float*)d_out;
    float* part = (float*)d_ws;   // B*CHUNKS*K floats = 1 MiB

    partial_sum_kernel<<<BB * CHUNKS, 256, 0, stream>>>(x, part);
    finish_kernel<<<BB * 4, 256, 0, stream>>>(part, w, out);
}